// Round 9
// baseline (446.693 us; speedup 1.0000x reference)
//
#include <hip/hip_runtime.h>

// ---------------------------------------------------------------------------
// AWQ int4 dequant GEMM: out = x @ dequant(qweight, scales, qzeros) + bias
// M=4096, K=4096, N=11008, group=128
//   1) convert_x: fp32->bf16 A[M][K]
//   2) dequant_awq: int4 -> bf16 Bt[N][K]
//   3) gemm_bf16: BM256 x BN128 x BK32, 512 thr, 8 waves (4M x 2N),
//      per-wave 64x64 (acc=64 regs), LDS 48 KiB -> 2 BLOCKS/CU (feasible
//      register budget, unlike R7), free-run body, XOR-swizzle, cluster map.
// ---------------------------------------------------------------------------

typedef __bf16 bf16x8 __attribute__((ext_vector_type(8)));
typedef float f32x4 __attribute__((ext_vector_type(4)));
typedef unsigned short ushort8 __attribute__((ext_vector_type(8)));

__device__ __forceinline__ unsigned short f2bf(float f) {
  unsigned int u = __builtin_bit_cast(unsigned int, f);
  u += 0x7FFFu + ((u >> 16) & 1u);
  return (unsigned short)(u >> 16);
}

__device__ __forceinline__ void gload16(const void* g, void* l) {
  __builtin_amdgcn_global_load_lds(
      (const __attribute__((address_space(1))) unsigned int*)g,
      (__attribute__((address_space(3))) unsigned int*)l, 16, 0, 0);
}

// ---------------------------------------------------------------------------
// Kernel 1: x fp32 -> A bf16
// ---------------------------------------------------------------------------
__global__ __launch_bounds__(256) void convert_x(const float* __restrict__ x,
                                                 unsigned short* __restrict__ A,
                                                 long long n8) {
  for (long long idx = (long long)blockIdx.x * 256 + threadIdx.x; idx < n8;
       idx += (long long)gridDim.x * 256) {
    float4 u = ((const float4*)x)[2 * idx];
    float4 v = ((const float4*)x)[2 * idx + 1];
    ushort8 o;
    o[0] = f2bf(u.x); o[1] = f2bf(u.y); o[2] = f2bf(u.z); o[3] = f2bf(u.w);
    o[4] = f2bf(v.x); o[5] = f2bf(v.y); o[6] = f2bf(v.z); o[7] = f2bf(v.w);
    ((ushort8*)A)[idx] = o;
  }
}

// ---------------------------------------------------------------------------
// Kernel 2: AWQ dequant + transpose -> Bt bf16 [N][K]
// ---------------------------------------------------------------------------
__global__ __launch_bounds__(256) void dequant_awq(const int* __restrict__ qw,
                                                   const float* __restrict__ sc,
                                                   const int* __restrict__ qz,
                                                   unsigned short* __restrict__ Bt,
                                                   int K, int N) {
  const int n8w = N >> 3;
  const int tiles_n = N >> 6;
  const int tk = blockIdx.x / tiles_n;
  const int tn = blockIdx.x % tiles_n;
  const int k0 = tk << 6, n0 = tn << 6;
  const int g = k0 >> 7;
  __shared__ unsigned short tile[64][72];
  __shared__ float s_s[64];
  __shared__ float s_z[64];
  const int t = threadIdx.x;
  if (t < 64) {
    s_s[t] = sc[(size_t)g * N + n0 + t];
  } else if (t < 72) {
    const int j = t - 64;
    const int zq = qz[(size_t)g * n8w + (n0 >> 3) + j];
    s_z[j * 8 + 0] = (float)((zq >> 0) & 0xF);
    s_z[j * 8 + 1] = (float)((zq >> 16) & 0xF);
    s_z[j * 8 + 2] = (float)((zq >> 4) & 0xF);
    s_z[j * 8 + 3] = (float)((zq >> 20) & 0xF);
    s_z[j * 8 + 4] = (float)((zq >> 8) & 0xF);
    s_z[j * 8 + 5] = (float)((zq >> 24) & 0xF);
    s_z[j * 8 + 6] = (float)((zq >> 12) & 0xF);
    s_z[j * 8 + 7] = (float)((zq >> 28) & 0xF);
  }
  __syncthreads();
#pragma unroll
  for (int r = 0; r < 2; ++r) {
    const int d = (r << 8) + t;
    const int kk = d >> 3, j = d & 7;
    const int q = qw[(size_t)(k0 + kk) * n8w + (n0 >> 3) + j];
    const int base = j << 3;
    ushort8 o;
    o[0] = f2bf(((float)((q >> 0) & 0xF) - s_z[base + 0]) * s_s[base + 0]);
    o[1] = f2bf(((float)((q >> 16) & 0xF) - s_z[base + 1]) * s_s[base + 1]);
    o[2] = f2bf(((float)((q >> 4) & 0xF) - s_z[base + 2]) * s_s[base + 2]);
    o[3] = f2bf(((float)((q >> 20) & 0xF) - s_z[base + 3]) * s_s[base + 3]);
    o[4] = f2bf(((float)((q >> 8) & 0xF) - s_z[base + 4]) * s_s[base + 4]);
    o[5] = f2bf(((float)((q >> 24) & 0xF) - s_z[base + 5]) * s_s[base + 5]);
    o[6] = f2bf(((float)((q >> 12) & 0xF) - s_z[base + 6]) * s_s[base + 6]);
    o[7] = f2bf(((float)((q >> 28) & 0xF) - s_z[base + 7]) * s_s[base + 7]);
    *(ushort8*)&tile[kk][base] = o;
  }
  __syncthreads();
#pragma unroll
  for (int r = 0; r < 2; ++r) {
    const int d = (r << 8) + t;
    const int nl = d >> 3, seg = d & 7;
    ushort8 o;
#pragma unroll
    for (int i = 0; i < 8; ++i) o[i] = tile[(seg << 3) + i][nl];
    *(ushort8*)&Bt[(size_t)(n0 + nl) * K + k0 + (seg << 3)] = o;
  }
}

// ---------------------------------------------------------------------------
// Kernel 3: 256x128xBK32 bf16 GEMM, 2 blocks/CU.  A [M][K], Bt [N][K].
// 8 waves (4M x 2N), per-wave 64x64 = acc[4][4] f32x4 (64 regs).
// LDS: 2 bufs x (A[256][32] + B[128][32]) = 48 KiB.
// Swizzle (R8-proven, 0 conflicts): row of 32 shorts = 4 chunks of 16B;
// physical chunk = logical ^ ((row>>1)&3); staging pre-swizzles the GLOBAL
// source (linear LDS dest, rule #21); reads apply the same XOR.
// Tile body (R6-proven free-run): stage t+1 (3 gload16/thread) -> 8 pinned
// ds_read_b128 -> lgkmcnt(2) MFMA half1 -> lgkmcnt(0) half2 -> vmcnt(0)
// -> barrier.  Cross-BLOCK TLP (2 independent blocks/CU) hides the stalls.
// ---------------------------------------------------------------------------
#define BM 256
#define BN 128
#define BK 32

__global__ __launch_bounds__(512, 4) void gemm_bf16(const unsigned short* __restrict__ A,
                                                    const unsigned short* __restrict__ Bt,
                                                    const float* __restrict__ bias,
                                                    float* __restrict__ C,
                                                    int M, int N, int K) {
  __shared__ __align__(16) unsigned short sm[2][12288];  // 48 KiB
  const int tid = threadIdx.x;
  const int w = tid >> 6, lane = tid & 63;
  const int wm = w >> 1, wn = w & 1;

  // cluster mapping: per XCD, clusters of 4bm x 16bn = 64 slots (2 blocks/CU
  // x 32 CUs).  nbm=16 -> 4 bm-clusters; nbn=86 -> 6 bn-clusters; nclu=24 = 3
  // rounds x 8 XCDs exactly.
  const int nbm = M / BM;                       // 16
  const int nbn = N / BN;                       // 86
  const int xcd = blockIdx.x & 7;
  const int slot = blockIdx.x >> 3;
  const int ci = xcd + 8 * (slot >> 6);         // 0..23
  const int t64 = slot & 63;
  const int cbm = ci & 3;
  const int cbn = ci >> 2;                      // 0..5
  const int bm = cbm * 4 + (t64 & 3);
  const int bn = cbn * 16 + (t64 >> 2);
  if (bm >= nbm || bn >= nbn) return;
  const int brow = bm * BM, bcol = bn * BN;

  // staging: thread covers A row tid>>2 (set0) and 128+(tid>>2) (set1), and
  // B row tid>>2.  phys chunk = tid&3; source logical chunk = phys ^ key(row),
  // key(row) = (row>>1)&3 -> schunk = (tid&3) ^ ((tid>>3)&3)  (row+128 same key).
  const int srow = tid >> 2;
  const int schunk = (tid & 3) ^ ((tid >> 3) & 3);
  const unsigned short* pA0 = A + (size_t)(brow + srow) * K + schunk * 8;
  const unsigned short* pA1 = A + (size_t)(brow + 128 + srow) * K + schunk * 8;
  const unsigned short* pB = Bt + (size_t)(bcol + srow) * K + schunk * 8;

  // fragment reads: row r = base + (lane&15), logical chunk = lane>>4,
  // physical chunk = (lane>>4) ^ ((r>>1)&3) = (lane>>4) ^ ((lane>>1)&3).
  const int xk = (lane >> 1) & 3;
  const int aOff = (wm * 64 + (lane & 15)) * 32 + 8 * ((lane >> 4) ^ xk);
  const int bOff = 8192 + (wn * 64 + (lane & 15)) * 32 + 8 * ((lane >> 4) ^ xk);

  const int NKt = K / BK;  // 128

  f32x4 acc[4][4];
#pragma unroll
  for (int m = 0; m < 4; ++m)
#pragma unroll
    for (int n = 0; n < 4; ++n) acc[m][n] = (f32x4){0.f, 0.f, 0.f, 0.f};

  auto stage_tile = [&](int kt) {
    const int buf = kt & 1;
    const size_t k0 = (size_t)kt * BK;
    // each wave writes 1 KiB (64 lanes x 16B) contiguous at base + 512*w shorts
    gload16(pA0 + k0, &sm[buf][512 * w]);
    gload16(pA1 + k0, &sm[buf][4096 + 512 * w]);
    gload16(pB + k0, &sm[buf][8192 + 512 * w]);
  };

  // prologue
  stage_tile(0);
  asm volatile("s_waitcnt vmcnt(0)" ::: "memory");
  __builtin_amdgcn_s_barrier();

  for (int t = 0; t < NKt; ++t) {
    const unsigned short* bp = sm[t & 1];

    if (t + 1 < NKt) stage_tile(t + 1);
    __builtin_amdgcn_sched_barrier(0);

    // pinned read order: a0,a1,b0,b1,b2,b3 | a2,a3
    bf16x8 a[4], b[4];
    a[0] = *(const bf16x8*)(bp + aOff);
    a[1] = *(const bf16x8*)(bp + aOff + 512);
#pragma unroll
    for (int n = 0; n < 4; ++n)
      b[n] = *(const bf16x8*)(bp + bOff + 512 * n);
    __builtin_amdgcn_sched_barrier(0);
    a[2] = *(const bf16x8*)(bp + aOff + 1024);
    a[3] = *(const bf16x8*)(bp + aOff + 1536);
    __builtin_amdgcn_sched_barrier(0);

    // half 1: m0-1 x n0-3 (first 6 reads done)
    asm volatile("s_waitcnt lgkmcnt(2)" ::: "memory");
    __builtin_amdgcn_sched_barrier(0);
    __builtin_amdgcn_s_setprio(1);
#pragma unroll
    for (int m = 0; m < 2; ++m)
#pragma unroll
      for (int n = 0; n < 4; ++n)
        acc[m][n] = __builtin_amdgcn_mfma_f32_16x16x32_bf16(a[m], b[n], acc[m][n], 0, 0, 0);
    __builtin_amdgcn_s_setprio(0);
    __builtin_amdgcn_sched_barrier(0);

    // half 2: m2-3 x n0-3
    asm volatile("s_waitcnt lgkmcnt(0)" ::: "memory");
    __builtin_amdgcn_sched_barrier(0);
    __builtin_amdgcn_s_setprio(1);
#pragma unroll
    for (int m = 2; m < 4; ++m)
#pragma unroll
      for (int n = 0; n < 4; ++n)
        acc[m][n] = __builtin_amdgcn_mfma_f32_16x16x32_bf16(a[m], b[n], acc[m][n], 0, 0, 0);
    __builtin_amdgcn_s_setprio(0);

    // staged data for t+1 landed; all waves' reads already drained
    asm volatile("s_waitcnt vmcnt(0)" ::: "memory");
    __builtin_amdgcn_s_barrier();
  }

  // epilogue: C/D layout col=lane&15, row=(lane>>4)*4+reg
#pragma unroll
  for (int n = 0; n < 4; ++n) {
    const int col = bcol + wn * 64 + n * 16 + (lane & 15);
    const float bv = bias[col];
#pragma unroll
    for (int m = 0; m < 4; ++m) {
      const int row0 = brow + wm * 64 + m * 16 + ((lane >> 4) << 2);
#pragma unroll
      for (int q = 0; q < 4; ++q)
        C[(size_t)(row0 + q) * N + col] = acc[m][n][q] + bv;
    }
  }
}

// ---------------------------------------------------------------------------
extern "C" void kernel_launch(void* const* d_in, const int* in_sizes, int n_in,
                              void* d_out, int out_size, void* d_ws, size_t ws_size,
                              hipStream_t stream) {
  const float* x = (const float*)d_in[0];
  const int* qw = (const int*)d_in[1];
  const float* sc = (const float*)d_in[2];
  const int* qz = (const int*)d_in[3];
  const float* bias = (const float*)d_in[4];
  float* out = (float*)d_out;

  const int N = in_sizes[4];                              // 11008
  const int K = (int)(((long long)in_sizes[1] * 8) / N);  // 4096
  const int M = in_sizes[0] / K;                          // 4096

  const size_t a_elems = (size_t)M * K;
  const size_t b_elems = (size_t)N * K;
  const size_t need = (a_elems + b_elems) * sizeof(unsigned short);
  if (ws_size < need) return;

  unsigned short* A = (unsigned short*)d_ws;
  unsigned short* Bt = A + a_elems;

  convert_x<<<2048, 256, 0, stream>>>(x, A, (long long)(a_elems / 8));
  dequant_awq<<<(K / 64) * (N / 64), 256, 0, stream>>>(qw, sc, qz, Bt, K, N);

  // clusters: 4bm x 16bn; nclu = 4 * 6 = 24 = 3 rounds x 8 XCDs
  const int grid = 8 * 64 * 3;  // 1536
  gemm_bf16<<<grid, 512, 0, stream>>>(A, Bt, bias, out, M, N, K);
}

// Round 11
// 439.525 us; speedup vs baseline: 1.0163x; 1.0163x over previous
//
#include <hip/hip_runtime.h>

// ---------------------------------------------------------------------------
// AWQ int4 dequant GEMM: out = x @ dequant(qweight, scales, qzeros) + bias
// M=4096, K=4096, N=11008, group=128
//   1) convert_x: fp32->bf16 A[M][K]
//   2) dequant_awq: int4 -> bf16 Bt[N][K]
//   3) gemm_bf16: FAT-WAVE 256x256xBK64, 256 thr (4 waves 2x2), per-wave
//      128x128, mfma_32x32x16, acc=256 VGPR @ 1 wave/SIMD, free-run body,
//      XOR-swizzle, cluster mapping.  lgkm gates <=8 (gfx9 4-bit field).
// ---------------------------------------------------------------------------

typedef __bf16 bf16x8 __attribute__((ext_vector_type(8)));
typedef float f32x16 __attribute__((ext_vector_type(16)));
typedef unsigned short ushort8 __attribute__((ext_vector_type(8)));

__device__ __forceinline__ unsigned short f2bf(float f) {
  unsigned int u = __builtin_bit_cast(unsigned int, f);
  u += 0x7FFFu + ((u >> 16) & 1u);
  return (unsigned short)(u >> 16);
}

__device__ __forceinline__ void gload16(const void* g, void* l) {
  __builtin_amdgcn_global_load_lds(
      (const __attribute__((address_space(1))) unsigned int*)g,
      (__attribute__((address_space(3))) unsigned int*)l, 16, 0, 0);
}

// ---------------------------------------------------------------------------
// Kernel 1: x fp32 -> A bf16
// ---------------------------------------------------------------------------
__global__ __launch_bounds__(256) void convert_x(const float* __restrict__ x,
                                                 unsigned short* __restrict__ A,
                                                 long long n8) {
  for (long long idx = (long long)blockIdx.x * 256 + threadIdx.x; idx < n8;
       idx += (long long)gridDim.x * 256) {
    float4 u = ((const float4*)x)[2 * idx];
    float4 v = ((const float4*)x)[2 * idx + 1];
    ushort8 o;
    o[0] = f2bf(u.x); o[1] = f2bf(u.y); o[2] = f2bf(u.z); o[3] = f2bf(u.w);
    o[4] = f2bf(v.x); o[5] = f2bf(v.y); o[6] = f2bf(v.z); o[7] = f2bf(v.w);
    ((ushort8*)A)[idx] = o;
  }
}

// ---------------------------------------------------------------------------
// Kernel 2: AWQ dequant + transpose -> Bt bf16 [N][K]
// ---------------------------------------------------------------------------
__global__ __launch_bounds__(256) void dequant_awq(const int* __restrict__ qw,
                                                   const float* __restrict__ sc,
                                                   const int* __restrict__ qz,
                                                   unsigned short* __restrict__ Bt,
                                                   int K, int N) {
  const int n8w = N >> 3;
  const int tiles_n = N >> 6;
  const int tk = blockIdx.x / tiles_n;
  const int tn = blockIdx.x % tiles_n;
  const int k0 = tk << 6, n0 = tn << 6;
  const int g = k0 >> 7;
  __shared__ unsigned short tile[64][72];
  __shared__ float s_s[64];
  __shared__ float s_z[64];
  const int t = threadIdx.x;
  if (t < 64) {
    s_s[t] = sc[(size_t)g * N + n0 + t];
  } else if (t < 72) {
    const int j = t - 64;
    const int zq = qz[(size_t)g * n8w + (n0 >> 3) + j];
    s_z[j * 8 + 0] = (float)((zq >> 0) & 0xF);
    s_z[j * 8 + 1] = (float)((zq >> 16) & 0xF);
    s_z[j * 8 + 2] = (float)((zq >> 4) & 0xF);
    s_z[j * 8 + 3] = (float)((zq >> 20) & 0xF);
    s_z[j * 8 + 4] = (float)((zq >> 8) & 0xF);
    s_z[j * 8 + 5] = (float)((zq >> 24) & 0xF);
    s_z[j * 8 + 6] = (float)((zq >> 12) & 0xF);
    s_z[j * 8 + 7] = (float)((zq >> 28) & 0xF);
  }
  __syncthreads();
#pragma unroll
  for (int r = 0; r < 2; ++r) {
    const int d = (r << 8) + t;
    const int kk = d >> 3, j = d & 7;
    const int q = qw[(size_t)(k0 + kk) * n8w + (n0 >> 3) + j];
    const int base = j << 3;
    ushort8 o;
    o[0] = f2bf(((float)((q >> 0) & 0xF) - s_z[base + 0]) * s_s[base + 0]);
    o[1] = f2bf(((float)((q >> 16) & 0xF) - s_z[base + 1]) * s_s[base + 1]);
    o[2] = f2bf(((float)((q >> 4) & 0xF) - s_z[base + 2]) * s_s[base + 2]);
    o[3] = f2bf(((float)((q >> 20) & 0xF) - s_z[base + 3]) * s_s[base + 3]);
    o[4] = f2bf(((float)((q >> 8) & 0xF) - s_z[base + 4]) * s_s[base + 4]);
    o[5] = f2bf(((float)((q >> 24) & 0xF) - s_z[base + 5]) * s_s[base + 5]);
    o[6] = f2bf(((float)((q >> 12) & 0xF) - s_z[base + 6]) * s_s[base + 6]);
    o[7] = f2bf(((float)((q >> 28) & 0xF) - s_z[base + 7]) * s_s[base + 7]);
    *(ushort8*)&tile[kk][base] = o;
  }
  __syncthreads();
#pragma unroll
  for (int r = 0; r < 2; ++r) {
    const int d = (r << 8) + t;
    const int nl = d >> 3, seg = d & 7;
    ushort8 o;
#pragma unroll
    for (int i = 0; i < 8; ++i) o[i] = tile[(seg << 3) + i][nl];
    *(ushort8*)&Bt[(size_t)(n0 + nl) * K + k0 + (seg << 3)] = o;
  }
}

// ---------------------------------------------------------------------------
// Kernel 3: fat-wave 256x256xBK64.  A [M][K], Bt [N][K], C fp32 [M][N].
// 4 waves (2M x 2N), per-wave 128x128 = acc[4][4] f32x16 (256 VGPR).
// mfma_f32_32x32x16_bf16: C/D col=lane&31, row=(reg&3)+8*(reg>>2)+4*(lane>>5).
// LDS: 2 bufs x (A[256][64] + B[256][64]) = 128 KiB.  Row = 8 chunks of
// 16B; phys chunk = logical ^ (row&7) (0-conflict); staging pre-swizzles
// the GLOBAL source (linear LDS dest, rule #21).
// Tile body: vmcnt(0) -> barrier -> stage t+1 (16 gload16) -> interleaved:
// issue ks0,ks1 reads -> lgkm(8) MFMA ks0 -> issue ks2 -> lgkm(8) MFMA ks1
// -> issue ks3 -> lgkm(8) MFMA ks2 -> lgkm(0) MFMA ks3.  One barrier/tile.
// ---------------------------------------------------------------------------
#define BM 256
#define BN 256
#define BK 64

__global__ __launch_bounds__(256, 1) void gemm_bf16(const unsigned short* __restrict__ A,
                                                    const unsigned short* __restrict__ Bt,
                                                    const float* __restrict__ bias,
                                                    float* __restrict__ C,
                                                    int M, int N, int K) {
  __shared__ __align__(16) unsigned short sm[2][32768];  // 128 KiB
  const int tid = threadIdx.x;
  const int w = tid >> 6, lane = tid & 63;
  const int wm = w >> 1, wn = w & 1;

  // cluster mapping (R6-proven): per XCD, 4bm x 8bn = 32 slots
  const int nbm = M / BM;                       // 16
  const int nbn = N / BN;                       // 43
  const int nclu = ((nbm + 3) >> 2) * ((nbn + 7) >> 3);
  const int xcd = blockIdx.x & 7;
  const int slot = blockIdx.x >> 3;
  const int ci = xcd + 8 * (slot >> 5);
  if (ci >= nclu) return;
  const int t32 = slot & 31;
  const int bm = (ci & 3) * 4 + (t32 & 3);
  const int bn = (ci >> 2) * 8 + (t32 >> 2);
  if (bm >= nbm || bn >= nbn) return;
  const int brow = bm * BM, bcol = bn * BN;

  // staging: wave w covers rows w*64 + i*8 + (lane>>3), i=0..7, for A and B.
  // phys chunk = lane&7; source logical chunk = (lane&7) ^ ((lane>>3)&7).
  const int srow = lane >> 3;
  const int schunk = (lane & 7) ^ srow;
  const unsigned short* pA = A + (size_t)(brow + w * 64 + srow) * K + schunk * 8;
  const unsigned short* pB = Bt + (size_t)(bcol + w * 64 + srow) * K + schunk * 8;

  // fragment reads: row r = base + (lane&31); logical chunk = ks*2 + (lane>>5);
  // phys = logical ^ (r&7); (r&7) = lane&7 since bases are mult of 32.
  const int r31 = lane & 31;
  const int khalf = lane >> 5;
  const int xkey = lane & 7;
  const int aRow = wm * 128 + r31;   // + mb*32
  const int bRow = wn * 128 + r31;   // + nb*32

  const int NKt = K / BK;  // 64

  f32x16 acc[4][4];
#pragma unroll
  for (int m = 0; m < 4; ++m)
#pragma unroll
    for (int n = 0; n < 4; ++n)
#pragma unroll
      for (int q = 0; q < 16; ++q) acc[m][n][q] = 0.f;

  auto stage_tile = [&](int kt) {
    const int buf = kt & 1;
    const size_t k0 = (size_t)kt * BK;
    unsigned short* dA = &sm[buf][w * 4096];
    unsigned short* dB = &sm[buf][16384 + w * 4096];
#pragma unroll
    for (int i = 0; i < 8; ++i) {
      gload16(pA + k0 + (size_t)(i * 8) * K, dA + i * 512);
      gload16(pB + k0 + (size_t)(i * 8) * K, dB + i * 512);
    }
  };

  stage_tile(0);

  for (int t = 0; t < NKt; ++t) {
    const unsigned short* bp = sm[t & 1];

    // own staged loads for tile t landed; barrier makes all waves' visible
    asm volatile("s_waitcnt vmcnt(0)" ::: "memory");
    __builtin_amdgcn_s_barrier();
    __builtin_amdgcn_sched_barrier(0);

    // stage t+1 (writes other buf; its readers drained it last tile)
    if (t + 1 < NKt) stage_tile(t + 1);
    __builtin_amdgcn_sched_barrier(0);

    bf16x8 a[4][4], b[4][4];  // [ks][mb/nb]
    auto issue_ks = [&](int ks) {
      const int chunk = ((ks * 2 + khalf) ^ xkey) * 8;
#pragma unroll
      for (int mb = 0; mb < 4; ++mb)
        a[ks][mb] = *(const bf16x8*)(bp + (aRow + mb * 32) * 64 + chunk);
#pragma unroll
      for (int nb = 0; nb < 4; ++nb)
        b[ks][nb] = *(const bf16x8*)(bp + 16384 + (bRow + nb * 32) * 64 + chunk);
    };
    auto mfma_ks = [&](int ks) {
      __builtin_amdgcn_s_setprio(1);
#pragma unroll
      for (int mb = 0; mb < 4; ++mb)
#pragma unroll
        for (int nb = 0; nb < 4; ++nb)
          acc[mb][nb] = __builtin_amdgcn_mfma_f32_32x32x16_bf16(
              a[ks][mb], b[ks][nb], acc[mb][nb], 0, 0, 0);
      __builtin_amdgcn_s_setprio(0);
    };

    issue_ks(0);
    __builtin_amdgcn_sched_barrier(0);
    issue_ks(1);
    __builtin_amdgcn_sched_barrier(0);

    asm volatile("s_waitcnt lgkmcnt(8)" ::: "memory");   // ks0 landed
    __builtin_amdgcn_sched_barrier(0);
    mfma_ks(0);
    __builtin_amdgcn_sched_barrier(0);
    issue_ks(2);
    __builtin_amdgcn_sched_barrier(0);

    asm volatile("s_waitcnt lgkmcnt(8)" ::: "memory");   // ks1 landed
    __builtin_amdgcn_sched_barrier(0);
    mfma_ks(1);
    __builtin_amdgcn_sched_barrier(0);
    issue_ks(3);
    __builtin_amdgcn_sched_barrier(0);

    asm volatile("s_waitcnt lgkmcnt(8)" ::: "memory");   // ks2 landed
    __builtin_amdgcn_sched_barrier(0);
    mfma_ks(2);
    __builtin_amdgcn_sched_barrier(0);

    asm volatile("s_waitcnt lgkmcnt(0)" ::: "memory");   // ks3 landed
    __builtin_amdgcn_sched_barrier(0);
    mfma_ks(3);
    __builtin_amdgcn_sched_barrier(0);
  }

  // epilogue: 32x32 C/D layout: col=lane&31, row=(reg&3)+8*(reg>>2)+4*(lane>>5)
#pragma unroll
  for (int nb = 0; nb < 4; ++nb) {
    const int col = bcol + wn * 128 + nb * 32 + r31;
    const float bv = bias[col];
#pragma unroll
    for (int mb = 0; mb < 4; ++mb) {
      const int rbase = brow + wm * 128 + mb * 32 + 4 * khalf;
#pragma unroll
      for (int q = 0; q < 16; ++q) {
        const int row = rbase + (q & 3) + 8 * (q >> 2);
        C[(size_t)row * N + col] = acc[mb][nb][q] + bv;
      }
    }
  }
}

// ---------------------------------------------------------------------------
extern "C" void kernel_launch(void* const* d_in, const int* in_sizes, int n_in,
                              void* d_out, int out_size, void* d_ws, size_t ws_size,
                              hipStream_t stream) {
  const float* x = (const float*)d_in[0];
  const int* qw = (const int*)d_in[1];
  const float* sc = (const float*)d_in[2];
  const int* qz = (const int*)d_in[3];
  const float* bias = (const float*)d_in[4];
  float* out = (float*)d_out;

  const int N = in_sizes[4];                              // 11008
  const int K = (int)(((long long)in_sizes[1] * 8) / N);  // 4096
  const int M = in_sizes[0] / K;                          // 4096

  const size_t a_elems = (size_t)M * K;
  const size_t b_elems = (size_t)N * K;
  const size_t need = (a_elems + b_elems) * sizeof(unsigned short);
  if (ws_size < need) return;

  unsigned short* A = (unsigned short*)d_ws;
  unsigned short* Bt = A + a_elems;

  convert_x<<<2048, 256, 0, stream>>>(x, A, (long long)(a_elems / 8));
  dequant_awq<<<(K / 64) * (N / 64), 256, 0, stream>>>(qw, sc, qz, Bt, K, N);

  const int nbm = M / BM, nbn = N / BN;
  const int nclu = ((nbm + 3) / 4) * ((nbn + 7) / 8);
  const int grid = 8 * 32 * ((nclu + 7) / 8);  // 768
  gemm_bf16<<<grid, 256, 0, stream>>>(A, Bt, bias, out, M, N, K);
}

// Round 12
// 409.833 us; speedup vs baseline: 1.0899x; 1.0725x over previous
//
#include <hip/hip_runtime.h>

// ---------------------------------------------------------------------------
// AWQ int4 dequant GEMM: out = x @ dequant(qweight, scales, qzeros) + bias
// M=4096, K=4096, N=11008, group=128
//   1) convert_x: fp32->bf16 A[M][K]
//   2) dequant_awq: int4 -> bf16 Bt[N][K]
//   3) gemm_bf16: R2's faithful 8-phase 256x256xBK64 template (counted
//      vmcnt(6), half-tile staging, 2 barriers/phase, setprio MFMA clusters,
//      XOR-swizzled LDS) + R6's XCD cluster mapping (4bm x 8bn per XCD,
//      FETCH 738->275 MB proven).  Single-variable composition test.
// ---------------------------------------------------------------------------

typedef __bf16 bf16x8 __attribute__((ext_vector_type(8)));
typedef float f32x4 __attribute__((ext_vector_type(4)));
typedef unsigned short ushort8 __attribute__((ext_vector_type(8)));

__device__ __forceinline__ unsigned short f2bf(float f) {
  unsigned int u = __builtin_bit_cast(unsigned int, f);
  u += 0x7FFFu + ((u >> 16) & 1u);
  return (unsigned short)(u >> 16);
}

__device__ __forceinline__ void gload16(const void* g, void* l) {
  __builtin_amdgcn_global_load_lds(
      (const __attribute__((address_space(1))) unsigned int*)g,
      (__attribute__((address_space(3))) unsigned int*)l, 16, 0, 0);
}

// ---------------------------------------------------------------------------
// Kernel 1: x fp32 -> A bf16
// ---------------------------------------------------------------------------
__global__ __launch_bounds__(256) void convert_x(const float* __restrict__ x,
                                                 unsigned short* __restrict__ A,
                                                 long long n8) {
  for (long long idx = (long long)blockIdx.x * 256 + threadIdx.x; idx < n8;
       idx += (long long)gridDim.x * 256) {
    float4 u = ((const float4*)x)[2 * idx];
    float4 v = ((const float4*)x)[2 * idx + 1];
    ushort8 o;
    o[0] = f2bf(u.x); o[1] = f2bf(u.y); o[2] = f2bf(u.z); o[3] = f2bf(u.w);
    o[4] = f2bf(v.x); o[5] = f2bf(v.y); o[6] = f2bf(v.z); o[7] = f2bf(v.w);
    ((ushort8*)A)[idx] = o;
  }
}

// ---------------------------------------------------------------------------
// Kernel 2: AWQ dequant + transpose -> Bt bf16 [N][K]
// ---------------------------------------------------------------------------
__global__ __launch_bounds__(256) void dequant_awq(const int* __restrict__ qw,
                                                   const float* __restrict__ sc,
                                                   const int* __restrict__ qz,
                                                   unsigned short* __restrict__ Bt,
                                                   int K, int N) {
  const int n8w = N >> 3;
  const int tiles_n = N >> 6;
  const int tk = blockIdx.x / tiles_n;
  const int tn = blockIdx.x % tiles_n;
  const int k0 = tk << 6, n0 = tn << 6;
  const int g = k0 >> 7;
  __shared__ unsigned short tile[64][72];
  __shared__ float s_s[64];
  __shared__ float s_z[64];
  const int t = threadIdx.x;
  if (t < 64) {
    s_s[t] = sc[(size_t)g * N + n0 + t];
  } else if (t < 72) {
    const int j = t - 64;
    const int zq = qz[(size_t)g * n8w + (n0 >> 3) + j];
    s_z[j * 8 + 0] = (float)((zq >> 0) & 0xF);
    s_z[j * 8 + 1] = (float)((zq >> 16) & 0xF);
    s_z[j * 8 + 2] = (float)((zq >> 4) & 0xF);
    s_z[j * 8 + 3] = (float)((zq >> 20) & 0xF);
    s_z[j * 8 + 4] = (float)((zq >> 8) & 0xF);
    s_z[j * 8 + 5] = (float)((zq >> 24) & 0xF);
    s_z[j * 8 + 6] = (float)((zq >> 12) & 0xF);
    s_z[j * 8 + 7] = (float)((zq >> 28) & 0xF);
  }
  __syncthreads();
#pragma unroll
  for (int r = 0; r < 2; ++r) {
    const int d = (r << 8) + t;
    const int kk = d >> 3, j = d & 7;
    const int q = qw[(size_t)(k0 + kk) * n8w + (n0 >> 3) + j];
    const int base = j << 3;
    ushort8 o;
    o[0] = f2bf(((float)((q >> 0) & 0xF) - s_z[base + 0]) * s_s[base + 0]);
    o[1] = f2bf(((float)((q >> 16) & 0xF) - s_z[base + 1]) * s_s[base + 1]);
    o[2] = f2bf(((float)((q >> 4) & 0xF) - s_z[base + 2]) * s_s[base + 2]);
    o[3] = f2bf(((float)((q >> 20) & 0xF) - s_z[base + 3]) * s_s[base + 3]);
    o[4] = f2bf(((float)((q >> 8) & 0xF) - s_z[base + 4]) * s_s[base + 4]);
    o[5] = f2bf(((float)((q >> 24) & 0xF) - s_z[base + 5]) * s_s[base + 5]);
    o[6] = f2bf(((float)((q >> 12) & 0xF) - s_z[base + 6]) * s_s[base + 6]);
    o[7] = f2bf(((float)((q >> 28) & 0xF) - s_z[base + 7]) * s_s[base + 7]);
    *(ushort8*)&tile[kk][base] = o;
  }
  __syncthreads();
#pragma unroll
  for (int r = 0; r < 2; ++r) {
    const int d = (r << 8) + t;
    const int nl = d >> 3, seg = d & 7;
    ushort8 o;
#pragma unroll
    for (int i = 0; i < 8; ++i) o[i] = tile[(seg << 3) + i][nl];
    *(ushort8*)&Bt[(size_t)(n0 + nl) * K + k0 + (seg << 3)] = o;
  }
}

// ---------------------------------------------------------------------------
// Kernel 3: 256x256 8-phase bf16 GEMM (R2 body) + cluster mapping (R6).
// 8 waves (2M x 4N), per-wave 128x64 output = acc[8][4] f32x4.
// LDS: 2 bufs x (A[256][64] + B[256][64]) = 128 KiB, XOR-swizzled content
// (k_shorts ^= (row&7)<<3) via pre-swizzled GLOBAL source (linear LDS dest).
// Half-tiles h: 0=A rows0-127, 1=A rows128-255, 2=B rows0-127, 3=B rows128-255.
// Stage slot at global phase p stages half index p+7 (prologue staged 0..6).
// vmcnt(6) once per K-tile (phase 4) => tile t+1 fully landed before use.
// ---------------------------------------------------------------------------
#define BM 256
#define BN 256
#define BK 64

__global__ __launch_bounds__(512, 2) void gemm_bf16(const unsigned short* __restrict__ A,
                                                    const unsigned short* __restrict__ Bt,
                                                    const float* __restrict__ bias,
                                                    float* __restrict__ C,
                                                    int M, int N, int K) {
  __shared__ __align__(16) unsigned short sm[2][32768];
  const int tid = threadIdx.x;
  const int w = tid >> 6, lane = tid & 63;
  const int wm = w >> 2, wn = w & 3;

  // cluster mapping (R6-proven): per XCD, 4bm x 8bn = 32 slots
  const int nbm = M / BM;                       // 16
  const int nbn = N / BN;                       // 43
  const int nclu = ((nbm + 3) >> 2) * ((nbn + 7) >> 3);
  const int xcd = blockIdx.x & 7;
  const int slot = blockIdx.x >> 3;
  const int ci = xcd + 8 * (slot >> 5);
  if (ci >= nclu) return;
  const int t32 = slot & 31;
  const int bm = (ci & 3) * 4 + (t32 & 3);
  const int bn = (ci >> 2) * 8 + (t32 >> 2);
  if (bm >= nbm || bn >= nbn) return;
  const int brow = bm * BM, bcol = bn * BN;

  // staging: thread covers row srow(+i*64+(h&1)*128), pre-swizzled k chunk
  const int srow = tid >> 3;                                // 0..63
  const int kswz = ((tid & 7) ^ (srow & 7)) << 3;           // shorts
  const unsigned short* pA = A + (size_t)(brow + srow) * K + kswz;
  const unsigned short* pB = Bt + (size_t)(bcol + srow) * K + kswz;

  // frag reads: row R = base + (lane&15); col bytes = (ks*64+q*16) ^ ((R&7)<<4)
  const int aBase = (wm * 128 + (lane & 15)) * 64;          // shorts
  const int bBase = 16384 + (wn * 64 + (lane & 15)) * 64;
  const int col0 = (((lane >> 4) * 16) ^ ((lane & 7) << 4)) >> 1;        // shorts
  const int col1 = ((64 + (lane >> 4) * 16) ^ ((lane & 7) << 4)) >> 1;

  const int NKt = K / BK;
  const int nhalf = NKt * 4;

  f32x4 acc[8][4];
#pragma unroll
  for (int m = 0; m < 8; ++m)
#pragma unroll
    for (int n = 0; n < 4; ++n) acc[m][n] = (f32x4){0.f, 0.f, 0.f, 0.f};

  auto stage_half = [&](int s) {
    if (s < nhalf) {
      const int kt = s >> 2, h = s & 3;
      const unsigned short* src =
          ((h & 2) ? pB : pA) + (size_t)((h & 1) * 128) * K + (size_t)kt * BK;
      unsigned short* dst = &sm[kt & 1][(h << 13) + (w << 9)];
      gload16(src, dst);
      gload16(src + (size_t)64 * K, dst + 4096);
    }
  };

  // prologue: tile0 (4 halves) + tile1 h0-2; wait tile0 landed
  for (int s = 0; s < 7; ++s) stage_half(s);
  asm volatile("s_waitcnt vmcnt(6)" ::: "memory");
  __builtin_amdgcn_s_barrier();

  for (int t = 0; t < NKt; ++t) {
    const unsigned short* bp = sm[t & 1];
    const int sb = 4 * t + 7;
    bf16x8 a0[4][2], a1[4][2], bb0[2][2], bb1[2][2];

    // ---- phase 1: read a0 (m0-3) + bb0 (n0-1); stage; MFMA q0 ----
#pragma unroll
    for (int m = 0; m < 4; ++m) {
      a0[m][0] = *(const bf16x8*)(bp + aBase + m * 1024 + col0);
      a0[m][1] = *(const bf16x8*)(bp + aBase + m * 1024 + col1);
    }
#pragma unroll
    for (int n = 0; n < 2; ++n) {
      bb0[n][0] = *(const bf16x8*)(bp + bBase + n * 1024 + col0);
      bb0[n][1] = *(const bf16x8*)(bp + bBase + n * 1024 + col1);
    }
    stage_half(sb + 0);
    __builtin_amdgcn_s_barrier();
    asm volatile("s_waitcnt lgkmcnt(0)" ::: "memory");
    __builtin_amdgcn_sched_barrier(0);
    __builtin_amdgcn_s_setprio(1);
#pragma unroll
    for (int kk = 0; kk < 2; ++kk)
#pragma unroll
      for (int m = 0; m < 4; ++m)
#pragma unroll
        for (int n = 0; n < 2; ++n)
          acc[m][n] = __builtin_amdgcn_mfma_f32_16x16x32_bf16(a0[m][kk], bb0[n][kk], acc[m][n], 0, 0, 0);
    __builtin_amdgcn_s_setprio(0);
    __builtin_amdgcn_s_barrier();

    // ---- phase 2: read a1 (m4-7); stage; MFMA q1 ----
#pragma unroll
    for (int m = 0; m < 4; ++m) {
      a1[m][0] = *(const bf16x8*)(bp + aBase + 4096 + m * 1024 + col0);
      a1[m][1] = *(const bf16x8*)(bp + aBase + 4096 + m * 1024 + col1);
    }
    stage_half(sb + 1);
    __builtin_amdgcn_s_barrier();
    asm volatile("s_waitcnt lgkmcnt(0)" ::: "memory");
    __builtin_amdgcn_sched_barrier(0);
    __builtin_amdgcn_s_setprio(1);
#pragma unroll
    for (int kk = 0; kk < 2; ++kk)
#pragma unroll
      for (int m = 0; m < 4; ++m)
#pragma unroll
        for (int n = 0; n < 2; ++n)
          acc[4 + m][n] = __builtin_amdgcn_mfma_f32_16x16x32_bf16(a1[m][kk], bb0[n][kk], acc[4 + m][n], 0, 0, 0);
    __builtin_amdgcn_s_setprio(0);
    __builtin_amdgcn_s_barrier();

    // ---- phase 3: read bb1 (n2-3); stage; MFMA q2 (reuses a0) ----
#pragma unroll
    for (int n = 0; n < 2; ++n) {
      bb1[n][0] = *(const bf16x8*)(bp + bBase + (n + 2) * 1024 + col0);
      bb1[n][1] = *(const bf16x8*)(bp + bBase + (n + 2) * 1024 + col1);
    }
    stage_half(sb + 2);
    __builtin_amdgcn_s_barrier();
    asm volatile("s_waitcnt lgkmcnt(0)" ::: "memory");
    __builtin_amdgcn_sched_barrier(0);
    __builtin_amdgcn_s_setprio(1);
#pragma unroll
    for (int kk = 0; kk < 2; ++kk)
#pragma unroll
      for (int m = 0; m < 4; ++m)
#pragma unroll
        for (int n = 0; n < 2; ++n)
          acc[m][2 + n] = __builtin_amdgcn_mfma_f32_16x16x32_bf16(a0[m][kk], bb1[n][kk], acc[m][2 + n], 0, 0, 0);
    __builtin_amdgcn_s_setprio(0);
    __builtin_amdgcn_s_barrier();

    // ---- phase 4: stage; counted vmcnt; MFMA q3 (reuses a1, bb1) ----
    stage_half(sb + 3);
    if (t < NKt - 2) {
      asm volatile("s_waitcnt vmcnt(6)" ::: "memory");
    } else {
      asm volatile("s_waitcnt vmcnt(0)" ::: "memory");
    }
    __builtin_amdgcn_s_barrier();
    __builtin_amdgcn_s_setprio(1);
#pragma unroll
    for (int kk = 0; kk < 2; ++kk)
#pragma unroll
      for (int m = 0; m < 4; ++m)
#pragma unroll
        for (int n = 0; n < 2; ++n)
          acc[4 + m][2 + n] = __builtin_amdgcn_mfma_f32_16x16x32_bf16(a1[m][kk], bb1[n][kk], acc[4 + m][2 + n], 0, 0, 0);
    __builtin_amdgcn_s_setprio(0);
    __builtin_amdgcn_s_barrier();
  }

  // epilogue: C/D layout col=lane&15, row=(lane>>4)*4+reg
#pragma unroll
  for (int n = 0; n < 4; ++n) {
    const int col = bcol + wn * 64 + n * 16 + (lane & 15);
    const float bv = bias[col];
#pragma unroll
    for (int m = 0; m < 8; ++m) {
      const int row0 = brow + wm * 128 + m * 16 + ((lane >> 4) << 2);
#pragma unroll
      for (int q = 0; q < 4; ++q)
        C[(size_t)(row0 + q) * N + col] = acc[m][n][q] + bv;
    }
  }
}

// ---------------------------------------------------------------------------
extern "C" void kernel_launch(void* const* d_in, const int* in_sizes, int n_in,
                              void* d_out, int out_size, void* d_ws, size_t ws_size,
                              hipStream_t stream) {
  const float* x = (const float*)d_in[0];
  const int* qw = (const int*)d_in[1];
  const float* sc = (const float*)d_in[2];
  const int* qz = (const int*)d_in[3];
  const float* bias = (const float*)d_in[4];
  float* out = (float*)d_out;

  const int N = in_sizes[4];                              // 11008
  const int K = (int)(((long long)in_sizes[1] * 8) / N);  // 4096
  const int M = in_sizes[0] / K;                          // 4096

  const size_t a_elems = (size_t)M * K;
  const size_t b_elems = (size_t)N * K;
  const size_t need = (a_elems + b_elems) * sizeof(unsigned short);
  if (ws_size < need) return;

  unsigned short* A = (unsigned short*)d_ws;
  unsigned short* Bt = A + a_elems;

  convert_x<<<2048, 256, 0, stream>>>(x, A, (long long)(a_elems / 8));
  dequant_awq<<<(K / 64) * (N / 64), 256, 0, stream>>>(qw, sc, qz, Bt, K, N);

  const int nbm = M / BM, nbn = N / BN;
  const int nclu = ((nbm + 3) / 4) * ((nbn + 7) / 8);
  const int grid = 8 * 32 * ((nclu + 7) / 8);  // 768
  gemm_bf16<<<grid, 512, 0, stream>>>(A, Bt, bias, out, M, N, K);
}